// Round 1
// baseline (932.755 us; speedup 1.0000x reference)
//
#include <hip/hip_runtime.h>

#define N_NODES   100000
#define N_EDGES   1600000
#define DIM       128
#define NUM_LAYERS 3

// ---------------- CSR build ----------------

__global__ void k_hist(const int* __restrict__ dst, int* __restrict__ deg) {
    int e = blockIdx.x * blockDim.x + threadIdx.x;
    if (e < N_EDGES) atomicAdd(&deg[dst[e]], 1);
}

__global__ void k_scan1(const int* __restrict__ deg, int* __restrict__ offs,
                        int* __restrict__ bsum) {
    __shared__ int s[1024];
    int t = threadIdx.x;
    int i = blockIdx.x * 1024 + t;
    int v = (i < N_NODES) ? deg[i] : 0;
    s[t] = v;
    __syncthreads();
    for (int off = 1; off < 1024; off <<= 1) {
        int tmp = 0;
        if (t >= off) tmp = s[t - off];
        __syncthreads();
        if (t >= off) s[t] += tmp;
        __syncthreads();
    }
    if (i < N_NODES) offs[i] = s[t] - v;        // exclusive within block
    if (t == 1023) bsum[blockIdx.x] = s[1023];  // block total
}

__global__ void k_scan2(int* __restrict__ bsum, int nb) {
    __shared__ int s[128];
    int t = threadIdx.x;
    int v = (t < nb) ? bsum[t] : 0;
    s[t] = v;
    __syncthreads();
    for (int off = 1; off < 128; off <<= 1) {
        int tmp = 0;
        if (t >= off) tmp = s[t - off];
        __syncthreads();
        if (t >= off) s[t] += tmp;
        __syncthreads();
    }
    if (t < nb) bsum[t] = s[t] - v;  // exclusive block bases
}

__global__ void k_scan3(int* __restrict__ offs, const int* __restrict__ bsum,
                        int* __restrict__ cur) {
    int i = blockIdx.x * blockDim.x + threadIdx.x;
    if (i < N_NODES) {
        int o = offs[i] + bsum[i >> 10];
        offs[i] = o;
        cur[i]  = o;
    }
}

__global__ void k_scatter(const int* __restrict__ src, const int* __restrict__ dst,
                          int* __restrict__ cur, int* __restrict__ ss) {
    int e = blockIdx.x * blockDim.x + threadIdx.x;
    if (e < N_EDGES) {
        int d = dst[e];
        int p = atomicAdd(&cur[d], 1);
        ss[p] = src[e];
    }
}

// ---------------- Aggregation: h[i] = x[i] + sum_{j in N(i)} x[j] ----------------
// 8 nodes per 256-thread block; 32 lanes per node, one float4 per lane (128 floats).

__global__ void k_agg(const float* __restrict__ x, const int* __restrict__ offs,
                      const int* __restrict__ deg, const int* __restrict__ ss,
                      float* __restrict__ h) {
    int g    = threadIdx.x >> 5;
    int lane = threadIdx.x & 31;
    int node = blockIdx.x * 8 + g;
    if (node >= N_NODES) return;
    const float4* xr = (const float4*)(x + (size_t)node * DIM);
    float4 acc = xr[lane];
    int start = offs[node];
    int len   = deg[node];
    for (int e = 0; e < len; ++e) {
        int s = ss[start + e];
        const float4* xs = (const float4*)(x + (size_t)s * DIM);
        float4 v = xs[lane];
        acc.x += v.x; acc.y += v.y; acc.z += v.z; acc.w += v.w;
    }
    ((float4*)(h + (size_t)node * DIM))[lane] = acc;
}

// ---------------- Fused MLP: out = [relu]( relu(h@W1+b1) @ W2 + b2 ) ----------------
// 256 threads, 32 rows/block. Thread: row-group rg (8 rows) x col-pair jp.
// fp32 vector FMAs; weights streamed from global (L2-resident, 64KB each).

template <int RELU_OUT>
__global__ __launch_bounds__(256) void k_mlp(
        const float* __restrict__ h,
        const float* __restrict__ W1, const float* __restrict__ b1,
        const float* __restrict__ W2, const float* __restrict__ b2,
        float* __restrict__ out) {
    __shared__ float hs[32][DIM];
    __shared__ float ts[32][DIM];
    int tid  = threadIdx.x;
    int row0 = blockIdx.x * 32;

    {   // stage 32 rows of h
        const float4* srcp = (const float4*)(h + (size_t)row0 * DIM);
        float4* dstp = (float4*)&hs[0][0];
        #pragma unroll
        for (int i = 0; i < 4; ++i) dstp[tid + 256 * i] = srcp[tid + 256 * i];
    }
    __syncthreads();

    int jp = (tid & 63) * 2;   // column pair
    int rg = tid >> 6;         // row group 0..3

    float acc0[8], acc1[8];
    #pragma unroll
    for (int r = 0; r < 8; ++r) { acc0[r] = 0.f; acc1[r] = 0.f; }

    for (int k0 = 0; k0 < DIM; k0 += 4) {
        float2 w0 = *(const float2*)&W1[(k0 + 0) * DIM + jp];
        float2 w1 = *(const float2*)&W1[(k0 + 1) * DIM + jp];
        float2 w2 = *(const float2*)&W1[(k0 + 2) * DIM + jp];
        float2 w3 = *(const float2*)&W1[(k0 + 3) * DIM + jp];
        #pragma unroll
        for (int r = 0; r < 8; ++r) {
            float4 hv = *(const float4*)&hs[rg * 8 + r][k0];
            acc0[r] += hv.x * w0.x + hv.y * w1.x + hv.z * w2.x + hv.w * w3.x;
            acc1[r] += hv.x * w0.y + hv.y * w1.y + hv.z * w2.y + hv.w * w3.y;
        }
    }
    {
        float bb0 = b1[jp], bb1 = b1[jp + 1];
        #pragma unroll
        for (int r = 0; r < 8; ++r) {
            float v0 = acc0[r] + bb0; v0 = v0 > 0.f ? v0 : 0.f;
            float v1 = acc1[r] + bb1; v1 = v1 > 0.f ? v1 : 0.f;
            *(float2*)&ts[rg * 8 + r][jp] = make_float2(v0, v1);
        }
    }
    __syncthreads();

    #pragma unroll
    for (int r = 0; r < 8; ++r) { acc0[r] = 0.f; acc1[r] = 0.f; }

    for (int k0 = 0; k0 < DIM; k0 += 4) {
        float2 w0 = *(const float2*)&W2[(k0 + 0) * DIM + jp];
        float2 w1 = *(const float2*)&W2[(k0 + 1) * DIM + jp];
        float2 w2 = *(const float2*)&W2[(k0 + 2) * DIM + jp];
        float2 w3 = *(const float2*)&W2[(k0 + 3) * DIM + jp];
        #pragma unroll
        for (int r = 0; r < 8; ++r) {
            float4 hv = *(const float4*)&ts[rg * 8 + r][k0];
            acc0[r] += hv.x * w0.x + hv.y * w1.x + hv.z * w2.x + hv.w * w3.x;
            acc1[r] += hv.x * w0.y + hv.y * w1.y + hv.z * w2.y + hv.w * w3.y;
        }
    }
    {
        float bb0 = b2[jp], bb1 = b2[jp + 1];
        #pragma unroll
        for (int r = 0; r < 8; ++r) {
            float v0 = acc0[r] + bb0;
            float v1 = acc1[r] + bb1;
            if (RELU_OUT) { v0 = v0 > 0.f ? v0 : 0.f; v1 = v1 > 0.f ? v1 : 0.f; }
            *(float2*)&out[(size_t)(row0 + rg * 8 + r) * DIM + jp] = make_float2(v0, v1);
        }
    }
}

// ---------------- launch ----------------

extern "C" void kernel_launch(void* const* d_in, const int* in_sizes, int n_in,
                              void* d_out, int out_size, void* d_ws, size_t ws_size,
                              hipStream_t stream) {
    const float* x  = (const float*)d_in[0];
    const int*   ei = (const int*)d_in[1];
    const float* W1 = (const float*)d_in[2];
    const float* b1 = (const float*)d_in[3];
    const float* W2 = (const float*)d_in[4];
    const float* b2 = (const float*)d_in[5];
    float* out = (float*)d_out;

    const int* src = ei;
    const int* dst = ei + N_EDGES;

    char* ws = (char*)d_ws;
    int* deg  = (int*)ws; ws += 100352 * 4;
    int* offs = (int*)ws; ws += 100352 * 4;
    int* cur  = (int*)ws; ws += 100352 * 4;
    int* bsum = (int*)ws; ws += 512;
    int* ss   = (int*)ws; ws += (size_t)N_EDGES * 4;
    float* bufA = (float*)ws;  // 100000*128 f32 = 51.2 MB

    // CSR build (per launch; deterministic work)
    hipMemsetAsync(deg, 0, 100352 * 4, stream);
    k_hist<<<(N_EDGES + 255) / 256, 256, 0, stream>>>(dst, deg);
    k_scan1<<<98, 1024, 0, stream>>>(deg, offs, bsum);
    k_scan2<<<1, 128, 0, stream>>>(bsum, 98);
    k_scan3<<<(N_NODES + 255) / 256, 256, 0, stream>>>(offs, bsum, cur);
    k_scatter<<<(N_EDGES + 255) / 256, 256, 0, stream>>>(src, dst, cur, ss);

    // 3 GIN layers; d_out doubles as the x ping-pong buffer.
    const float* xin = x;
    for (int l = 0; l < NUM_LAYERS; ++l) {
        k_agg<<<(N_NODES + 7) / 8, 256, 0, stream>>>(xin, offs, deg, ss, bufA);
        const float* w1l = W1 + (size_t)l * DIM * DIM;
        const float* b1l = b1 + (size_t)l * DIM;
        const float* w2l = W2 + (size_t)l * DIM * DIM;
        const float* b2l = b2 + (size_t)l * DIM;
        if (l < NUM_LAYERS - 1)
            k_mlp<1><<<N_NODES / 32, 256, 0, stream>>>(bufA, w1l, b1l, w2l, b2l, out);
        else
            k_mlp<0><<<N_NODES / 32, 256, 0, stream>>>(bufA, w1l, b1l, w2l, b2l, out);
        xin = out;
    }
}

// Round 2
// 575.433 us; speedup vs baseline: 1.6210x; 1.6210x over previous
//
#include <hip/hip_runtime.h>

#define N_NODES   100000
#define N_EDGES   1600000
#define DIM       128
#define NUM_LAYERS 3

typedef __attribute__((ext_vector_type(8))) short short8;
typedef __attribute__((ext_vector_type(4))) float f32x4;

#define MFMA_BF16(acc, a, b) \
    asm("v_mfma_f32_16x16x32_bf16 %0, %1, %2, %0" : "+v"(acc) : "v"(a), "v"(b))

__device__ __forceinline__ unsigned short f2bf(float f) {
    unsigned int u = __builtin_bit_cast(unsigned int, f);
    unsigned int r = (u + 0x7FFFu + ((u >> 16) & 1u)) >> 16;   // RNE
    return (unsigned short)r;
}
__device__ __forceinline__ float bflo(unsigned int p) {  // low bf16 of packed pair
    return __builtin_bit_cast(float, p << 16);
}
__device__ __forceinline__ float bfhi(unsigned int p) {  // high bf16
    return __builtin_bit_cast(float, p & 0xFFFF0000u);
}

// ---------------- prep: f32 -> bf16 ----------------

__global__ void k_cvt(const float* __restrict__ x, unsigned short* __restrict__ xb) {
    int i = blockIdx.x * 256 + threadIdx.x;               // one float4 per thread
    float4 v = ((const float4*)x)[i];
    uint2 o;
    o.x = (unsigned int)f2bf(v.x) | ((unsigned int)f2bf(v.y) << 16);
    o.y = (unsigned int)f2bf(v.z) | ((unsigned int)f2bf(v.w) << 16);
    ((uint2*)xb)[i] = o;
}

// Shuffle W1/W2 (3 layers each) into exact B-fragment order:
// frag element o = ((t*4+kk)*64 + lane)*8 + i  <-  W[k=32kk+8*(lane>>4)+i][n=16t+(lane&15)]
__global__ void k_wprep(const float* __restrict__ W1, const float* __restrict__ W2,
                        unsigned short* __restrict__ wb) {
    int o = blockIdx.x * 256 + threadIdx.x;               // 6*16384 total
    int m   = o >> 14;
    int idx = o & 16383;
    int i    = idx & 7;
    int lane = (idx >> 3) & 63;
    int kk   = (idx >> 9) & 3;
    int t    = idx >> 11;
    int k = kk * 32 + (lane >> 4) * 8 + i;
    int n = t * 16 + (lane & 15);
    const float* Wsrc = (m < 3) ? (W1 + (size_t)m * 16384) : (W2 + (size_t)(m - 3) * 16384);
    wb[o] = f2bf(Wsrc[k * 128 + n]);
}

// ---------------- CSR build ----------------

__global__ void k_hist(const int* __restrict__ dst, int* __restrict__ deg) {
    int e = blockIdx.x * blockDim.x + threadIdx.x;
    if (e < N_EDGES) atomicAdd(&deg[dst[e]], 1);
}

__global__ void k_scan1(const int* __restrict__ deg, int* __restrict__ offs,
                        int* __restrict__ bsum) {
    __shared__ int s[1024];
    int t = threadIdx.x;
    int i = blockIdx.x * 1024 + t;
    int v = (i < N_NODES) ? deg[i] : 0;
    s[t] = v;
    __syncthreads();
    for (int off = 1; off < 1024; off <<= 1) {
        int tmp = 0;
        if (t >= off) tmp = s[t - off];
        __syncthreads();
        if (t >= off) s[t] += tmp;
        __syncthreads();
    }
    if (i < N_NODES) offs[i] = s[t] - v;
    if (t == 1023) bsum[blockIdx.x] = s[1023];
}

__global__ void k_scan2(int* __restrict__ bsum, int nb) {
    __shared__ int s[128];
    int t = threadIdx.x;
    int v = (t < nb) ? bsum[t] : 0;
    s[t] = v;
    __syncthreads();
    for (int off = 1; off < 128; off <<= 1) {
        int tmp = 0;
        if (t >= off) tmp = s[t - off];
        __syncthreads();
        if (t >= off) s[t] += tmp;
        __syncthreads();
    }
    if (t < nb) bsum[t] = s[t] - v;
}

__global__ void k_scan3(int* __restrict__ offs, const int* __restrict__ bsum,
                        int* __restrict__ cur) {
    int i = blockIdx.x * blockDim.x + threadIdx.x;
    if (i < N_NODES) {
        int o = offs[i] + bsum[i >> 10];
        offs[i] = o;
        cur[i]  = o;
    }
}

__global__ void k_scatter(const int* __restrict__ src, const int* __restrict__ dst,
                          int* __restrict__ cur, int* __restrict__ ss) {
    int e = blockIdx.x * blockDim.x + threadIdx.x;
    if (e < N_EDGES) {
        int d = dst[e];
        int p = atomicAdd(&cur[d], 1);
        ss[p] = src[e];
    }
}

// ---------------- Aggregation (bf16): h[i] = x[i] + sum_j x[j] ----------------
// 8 nodes / 256-thread block; 32 lanes per node, uint2 (4 bf16) per lane.

__global__ void k_agg(const unsigned short* __restrict__ xb, const int* __restrict__ offs,
                      const int* __restrict__ deg, const int* __restrict__ ss,
                      unsigned short* __restrict__ hb) {
    int g    = threadIdx.x >> 5;
    int lane = threadIdx.x & 31;
    int node = blockIdx.x * 8 + g;
    uint2 sv = ((const uint2*)(xb + (size_t)node * DIM))[lane];
    float a0 = bflo(sv.x), a1 = bfhi(sv.x), a2 = bflo(sv.y), a3 = bfhi(sv.y);
    int start = offs[node];
    int len   = deg[node];
    for (int e = 0; e < len; ++e) {
        int s = ss[start + e];
        uint2 v = ((const uint2*)(xb + (size_t)s * DIM))[lane];
        a0 += bflo(v.x); a1 += bfhi(v.x); a2 += bflo(v.y); a3 += bfhi(v.y);
    }
    uint2 o;
    o.x = (unsigned int)f2bf(a0) | ((unsigned int)f2bf(a1) << 16);
    o.y = (unsigned int)f2bf(a2) | ((unsigned int)f2bf(a3) << 16);
    ((uint2*)(hb + (size_t)node * DIM))[lane] = o;
}

// ---------------- MFMA MLP: out = [relu]( relu(h@W1+b1) @ W2 + b2 ) ----------------
// 4 waves/block, 16 rows/wave. 8 n-tiles x 4 k-steps of 16x16x32 bf16 per GEMM.
// GEMM1 -> GEMM2 handoff via per-wave LDS tile, padded stride 136 ushorts.

template <int FINAL>
__global__ __launch_bounds__(256) void k_mlp(
        const unsigned short* __restrict__ hb,
        const unsigned short* __restrict__ w1b, const float* __restrict__ b1,
        const unsigned short* __restrict__ w2b, const float* __restrict__ b2,
        unsigned short* __restrict__ outb, float* __restrict__ outf) {
    __shared__ unsigned short Ts[4][16][136];
    int tid  = threadIdx.x;
    int w    = tid >> 6;
    int lane = tid & 63;
    int r0   = blockIdx.x * 64 + w * 16;
    bool live = (r0 < N_NODES);
    if (!live) r0 = N_NODES - 16;      // reads stay in-bounds; stores masked below
    int lrow = lane & 15;
    int lgrp = lane >> 4;

    const short8* hb8  = (const short8*)hb;
    const short8* w1f  = (const short8*)w1b;
    const short8* w2f  = (const short8*)w2b;

    f32x4 acc[8];
    #pragma unroll
    for (int t = 0; t < 8; ++t) acc[t] = (f32x4){0.f, 0.f, 0.f, 0.f};

    // GEMM1: A from global hb, B from pre-shuffled w1b
    #pragma unroll
    for (int kk = 0; kk < 4; ++kk) {
        short8 a = hb8[(size_t)(r0 + lrow) * 16 + kk * 4 + lgrp];
        const short8* bp = w1f + kk * 64 + lane;
        #pragma unroll
        for (int t = 0; t < 8; ++t) {
            short8 b = bp[t * 256];
            MFMA_BF16(acc[t], a, b);
        }
    }

    // epilogue1: bias + relu -> bf16 -> LDS (per-wave tile)
    #pragma unroll
    for (int t = 0; t < 8; ++t) {
        float bb = b1[t * 16 + lrow];
        #pragma unroll
        for (int r = 0; r < 4; ++r) {
            float v = acc[t][r] + bb;
            v = fmaxf(v, 0.f);
            Ts[w][lgrp * 4 + r][t * 16 + lrow] = f2bf(v);
        }
        acc[t] = (f32x4){0.f, 0.f, 0.f, 0.f};
    }
    __syncthreads();

    // GEMM2: A from LDS (ds_read_b128), B from w2b
    #pragma unroll
    for (int kk = 0; kk < 4; ++kk) {
        short8 a = *(const short8*)&Ts[w][lrow][kk * 32 + lgrp * 8];
        const short8* bp = w2f + kk * 64 + lane;
        #pragma unroll
        for (int t = 0; t < 8; ++t) {
            short8 b = bp[t * 256];
            MFMA_BF16(acc[t], a, b);
        }
    }

    // epilogue2
    #pragma unroll
    for (int t = 0; t < 8; ++t) {
        float bb = b2[t * 16 + lrow];
        #pragma unroll
        for (int r = 0; r < 4; ++r) {
            float v = acc[t][r] + bb;
            size_t oi = (size_t)(r0 + lgrp * 4 + r) * DIM + t * 16 + lrow;
            if (FINAL) {
                if (live) outf[oi] = v;
            } else {
                v = fmaxf(v, 0.f);
                if (live) outb[oi] = f2bf(v);
            }
        }
    }
}

// ---------------- launch ----------------

extern "C" void kernel_launch(void* const* d_in, const int* in_sizes, int n_in,
                              void* d_out, int out_size, void* d_ws, size_t ws_size,
                              hipStream_t stream) {
    const float* x  = (const float*)d_in[0];
    const int*   ei = (const int*)d_in[1];
    const float* W1 = (const float*)d_in[2];
    const float* b1 = (const float*)d_in[3];
    const float* W2 = (const float*)d_in[4];
    const float* b2 = (const float*)d_in[5];
    float* out = (float*)d_out;

    const int* src = ei;
    const int* dst = ei + N_EDGES;

    char* ws = (char*)d_ws;
    int* deg  = (int*)ws; ws += 100352 * 4;
    int* offs = (int*)ws; ws += 100352 * 4;
    int* cur  = (int*)ws; ws += 100352 * 4;
    int* bsum = (int*)ws; ws += 512;
    int* ss   = (int*)ws; ws += (size_t)N_EDGES * 4;
    unsigned short* wb = (unsigned short*)ws; ws += 6 * 16384 * 2;
    unsigned short* hb = (unsigned short*)ws; ws += (size_t)N_NODES * DIM * 2;
    unsigned short* xb = (unsigned short*)ws; ws += (size_t)N_NODES * DIM * 2 + 32768;
    // hb overruns (dead-wave reads) land inside xb; xb never overruns.

    // prep
    k_cvt  <<<12500, 256, 0, stream>>>(x, xb);
    k_wprep<<<384,   256, 0, stream>>>(W1, W2, wb);

    // CSR build
    hipMemsetAsync(deg, 0, 100352 * 4, stream);
    k_hist   <<<(N_EDGES + 255) / 256, 256, 0, stream>>>(dst, deg);
    k_scan1  <<<98, 1024, 0, stream>>>(deg, offs, bsum);
    k_scan2  <<<1, 128, 0, stream>>>(bsum, 98);
    k_scan3  <<<(N_NODES + 255) / 256, 256, 0, stream>>>(offs, bsum, cur);
    k_scatter<<<(N_EDGES + 255) / 256, 256, 0, stream>>>(src, dst, cur, ss);

    // 3 GIN layers: agg(xb -> hb), mlp(hb -> xb or out)
    for (int l = 0; l < NUM_LAYERS; ++l) {
        k_agg<<<12500, 256, 0, stream>>>(xb, offs, deg, ss, hb);
        const unsigned short* w1l = wb + (size_t)l * 16384;
        const unsigned short* w2l = wb + (size_t)(3 + l) * 16384;
        const float* b1l = b1 + (size_t)l * DIM;
        const float* b2l = b2 + (size_t)l * DIM;
        if (l < NUM_LAYERS - 1)
            k_mlp<0><<<1563, 256, 0, stream>>>(hb, w1l, b1l, w2l, b2l, xb, nullptr);
        else
            k_mlp<1><<<1563, 256, 0, stream>>>(hb, w1l, b1l, w2l, b2l, nullptr, out);
    }
}

// Round 3
// 419.973 us; speedup vs baseline: 2.2210x; 1.3702x over previous
//
#include <hip/hip_runtime.h>

#define N_NODES   100000
#define N_EDGES   1600000
#define DIM       128
#define NUM_LAYERS 3

#define NB   391          // buckets of 256 dst-nodes
#define BCAP 8192         // staging capacity per bucket (mean 4092, sigma 64)

typedef __attribute__((ext_vector_type(8))) short short8;
typedef __attribute__((ext_vector_type(4))) float f32x4;

#define MFMA_BF16(acc, a, b) \
    asm("v_mfma_f32_16x16x32_bf16 %0, %1, %2, %0" : "+v"(acc) : "v"(a), "v"(b))

__device__ __forceinline__ unsigned short f2bf(float f) {
    unsigned int u = __builtin_bit_cast(unsigned int, f);
    unsigned int r = (u + 0x7FFFu + ((u >> 16) & 1u)) >> 16;   // RNE
    return (unsigned short)r;
}
__device__ __forceinline__ float bflo(unsigned int p) {
    return __builtin_bit_cast(float, p << 16);
}
__device__ __forceinline__ float bfhi(unsigned int p) {
    return __builtin_bit_cast(float, p & 0xFFFF0000u);
}

// ---------------- prep: f32 -> bf16 ----------------

__global__ void k_cvt(const float* __restrict__ x, unsigned short* __restrict__ xb) {
    int i = blockIdx.x * 256 + threadIdx.x;
    float4 v = ((const float4*)x)[i];
    uint2 o;
    o.x = (unsigned int)f2bf(v.x) | ((unsigned int)f2bf(v.y) << 16);
    o.y = (unsigned int)f2bf(v.z) | ((unsigned int)f2bf(v.w) << 16);
    ((uint2*)xb)[i] = o;
}

__global__ void k_wprep(const float* __restrict__ W1, const float* __restrict__ W2,
                        unsigned short* __restrict__ wb) {
    int o = blockIdx.x * 256 + threadIdx.x;
    int m   = o >> 14;
    int idx = o & 16383;
    int i    = idx & 7;
    int lane = (idx >> 3) & 63;
    int kk   = (idx >> 9) & 3;
    int t    = idx >> 11;
    int k = kk * 32 + (lane >> 4) * 8 + i;
    int n = t * 16 + (lane & 15);
    const float* Wsrc = (m < 3) ? (W1 + (size_t)m * 16384) : (W2 + (size_t)(m - 3) * 16384);
    wb[o] = f2bf(Wsrc[k * 128 + n]);
}

// ---------------- CSR build: bucketed counting sort ----------------

__global__ void k_binit(int* __restrict__ gcur) {
    int i = threadIdx.x;
    if (i < NB) gcur[i] = i * BCAP;
}

// Pass A: bin edges into per-bucket staging (bucket = dst>>8).
// 1024 thr x 16 edges. LDS hist -> one reservation atomic per (block,bucket).
__global__ __launch_bounds__(1024) void k_bin(
        const int* __restrict__ src, const int* __restrict__ dst,
        int* __restrict__ gcur, unsigned int* __restrict__ staging) {
    __shared__ int h[NB];
    __shared__ int base[NB];
    int tid = threadIdx.x;
    for (int i = tid; i < NB; i += 1024) h[i] = 0;
    __syncthreads();
    int e0 = blockIdx.x * 16384;
    unsigned int rec[16];
    int bk[16];
    #pragma unroll
    for (int k = 0; k < 16; ++k) {
        int e = e0 + k * 1024 + tid;
        if (e < N_EDGES) {
            int d = dst[e];
            int b = d >> 8;
            bk[k] = b;
            rec[k] = (unsigned int)src[e] | ((unsigned int)(d & 255) << 17);
            atomicAdd(&h[b], 1);
        } else bk[k] = -1;
    }
    __syncthreads();
    for (int i = tid; i < NB; i += 1024) {
        int c = h[i];
        base[i] = (c > 0) ? atomicAdd(&gcur[i], c) : 0;
    }
    __syncthreads();
    for (int i = tid; i < NB; i += 1024) h[i] = 0;
    __syncthreads();
    #pragma unroll
    for (int k = 0; k < 16; ++k) {
        if (bk[k] >= 0) {
            int p = base[bk[k]] + atomicAdd(&h[bk[k]], 1);
            staging[p] = rec[k];
        }
    }
}

// scan bucket counts -> exclusive edge bases
__global__ void k_bscan(const int* __restrict__ gcur, int* __restrict__ ebase) {
    __shared__ int s[512];
    int t = threadIdx.x;
    int v = (t < NB) ? (gcur[t] - t * BCAP) : 0;
    s[t] = v;
    __syncthreads();
    for (int off = 1; off < 512; off <<= 1) {
        int tmp = 0;
        if (t >= off) tmp = s[t - off];
        __syncthreads();
        if (t >= off) s[t] += tmp;
        __syncthreads();
    }
    if (t < NB) ebase[t] = s[t] - v;
}

// Pass B: per bucket, per-node hist + scan -> offs; scatter srcs into ss
// within the bucket's window (L2-merged writes). Also yields monotone offs,
// so deg[i] = offs[i+1]-offs[i].
__global__ __launch_bounds__(256) void k_build(
        const unsigned int* __restrict__ staging, const int* __restrict__ gcur,
        const int* __restrict__ ebase, int* __restrict__ offs, int* __restrict__ ss) {
    __shared__ int h[256];
    __shared__ int s[256];
    int b = blockIdx.x, t = threadIdx.x;
    int cnt = gcur[b] - b * BCAP;
    const unsigned int* seg = staging + (size_t)b * BCAP;
    h[t] = 0;
    __syncthreads();
    for (int i = t; i < cnt; i += 256) atomicAdd(&h[seg[i] >> 17], 1);
    __syncthreads();
    int v = h[t];
    s[t] = v;
    __syncthreads();
    for (int off = 1; off < 256; off <<= 1) {
        int tmp = 0;
        if (t >= off) tmp = s[t - off];
        __syncthreads();
        if (t >= off) s[t] += tmp;
        __syncthreads();
    }
    int eb = ebase[b];
    int excl = eb + s[t] - v;          // global CSR offset for node b*256+t
    offs[b * 256 + t] = excl;
    __syncthreads();
    h[t] = excl;                        // per-node cursor
    __syncthreads();
    for (int i = t; i < cnt; i += 256) {
        unsigned int r = seg[i];
        int pos = atomicAdd(&h[r >> 17], 1);
        ss[pos] = (int)(r & 0x1FFFFu);
    }
}

// ---------------- Aggregation (bf16): h[i] = x[i] + sum_j x[j] ----------------

__global__ void k_agg(const unsigned short* __restrict__ xb, const int* __restrict__ offs,
                      const int* __restrict__ ss, unsigned short* __restrict__ hb) {
    int g    = threadIdx.x >> 5;
    int lane = threadIdx.x & 31;
    int node = blockIdx.x * 8 + g;
    uint2 sv = ((const uint2*)(xb + (size_t)node * DIM))[lane];
    float a0 = bflo(sv.x), a1 = bfhi(sv.x), a2 = bflo(sv.y), a3 = bfhi(sv.y);
    int start = offs[node];
    int end   = offs[node + 1];
    for (int e = start; e < end; ++e) {
        int sidx = ss[e];
        uint2 v = ((const uint2*)(xb + (size_t)sidx * DIM))[lane];
        a0 += bflo(v.x); a1 += bfhi(v.x); a2 += bflo(v.y); a3 += bfhi(v.y);
    }
    uint2 o;
    o.x = (unsigned int)f2bf(a0) | ((unsigned int)f2bf(a1) << 16);
    o.y = (unsigned int)f2bf(a2) | ((unsigned int)f2bf(a3) << 16);
    ((uint2*)(hb + (size_t)node * DIM))[lane] = o;
}

// ---------------- MFMA MLP ----------------

template <int FINAL>
__global__ __launch_bounds__(256) void k_mlp(
        const unsigned short* __restrict__ hb,
        const unsigned short* __restrict__ w1b, const float* __restrict__ b1,
        const unsigned short* __restrict__ w2b, const float* __restrict__ b2,
        unsigned short* __restrict__ outb, float* __restrict__ outf) {
    __shared__ unsigned short Ts[4][16][136];
    int tid  = threadIdx.x;
    int w    = tid >> 6;
    int lane = tid & 63;
    int r0   = blockIdx.x * 64 + w * 16;
    bool live = (r0 < N_NODES);
    if (!live) r0 = N_NODES - 16;
    int lrow = lane & 15;
    int lgrp = lane >> 4;

    const short8* hb8  = (const short8*)hb;
    const short8* w1f  = (const short8*)w1b;
    const short8* w2f  = (const short8*)w2b;

    f32x4 acc[8];
    #pragma unroll
    for (int t = 0; t < 8; ++t) acc[t] = (f32x4){0.f, 0.f, 0.f, 0.f};

    #pragma unroll
    for (int kk = 0; kk < 4; ++kk) {
        short8 a = hb8[(size_t)(r0 + lrow) * 16 + kk * 4 + lgrp];
        const short8* bp = w1f + kk * 64 + lane;
        #pragma unroll
        for (int t = 0; t < 8; ++t) {
            short8 b = bp[t * 256];
            MFMA_BF16(acc[t], a, b);
        }
    }

    #pragma unroll
    for (int t = 0; t < 8; ++t) {
        float bb = b1[t * 16 + lrow];
        #pragma unroll
        for (int r = 0; r < 4; ++r) {
            float v = acc[t][r] + bb;
            v = fmaxf(v, 0.f);
            Ts[w][lgrp * 4 + r][t * 16 + lrow] = f2bf(v);
        }
        acc[t] = (f32x4){0.f, 0.f, 0.f, 0.f};
    }
    __syncthreads();

    #pragma unroll
    for (int kk = 0; kk < 4; ++kk) {
        short8 a = *(const short8*)&Ts[w][lrow][kk * 32 + lgrp * 8];
        const short8* bp = w2f + kk * 64 + lane;
        #pragma unroll
        for (int t = 0; t < 8; ++t) {
            short8 b = bp[t * 256];
            MFMA_BF16(acc[t], a, b);
        }
    }

    #pragma unroll
    for (int t = 0; t < 8; ++t) {
        float bb = b2[t * 16 + lrow];
        #pragma unroll
        for (int r = 0; r < 4; ++r) {
            float v = acc[t][r] + bb;
            size_t oi = (size_t)(r0 + lgrp * 4 + r) * DIM + t * 16 + lrow;
            if (FINAL) {
                if (live) outf[oi] = v;
            } else {
                v = fmaxf(v, 0.f);
                if (live) outb[oi] = f2bf(v);
            }
        }
    }
}

// ---------------- launch ----------------

extern "C" void kernel_launch(void* const* d_in, const int* in_sizes, int n_in,
                              void* d_out, int out_size, void* d_ws, size_t ws_size,
                              hipStream_t stream) {
    const float* x  = (const float*)d_in[0];
    const int*   ei = (const int*)d_in[1];
    const float* W1 = (const float*)d_in[2];
    const float* b1 = (const float*)d_in[3];
    const float* W2 = (const float*)d_in[4];
    const float* b2 = (const float*)d_in[5];
    float* out = (float*)d_out;

    const int* src = ei;
    const int* dst = ei + N_EDGES;

    char* ws = (char*)d_ws;
    int* gcur  = (int*)ws; ws += 2048;
    int* ebase = (int*)ws; ws += 2048;
    int* offs  = (int*)ws; ws += 100352 * 4;            // 100096 used (+1 sentinel inside)
    int* ss    = (int*)ws; ws += (size_t)N_EDGES * 4;
    unsigned short* wb = (unsigned short*)ws; ws += 6 * 16384 * 2;
    unsigned short* hb = (unsigned short*)ws;           // 25.6 MB
    unsigned int* staging = (unsigned int*)hb;          // 12.8 MB, dead before first k_agg
    ws += (size_t)N_NODES * DIM * 2;
    unsigned short* xb = (unsigned short*)ws; ws += (size_t)N_NODES * DIM * 2;

    // prep
    k_cvt  <<<12500, 256, 0, stream>>>(x, xb);
    k_wprep<<<384,   256, 0, stream>>>(W1, W2, wb);

    // CSR build: bucketed counting sort
    k_binit<<<1, 512, 0, stream>>>(gcur);
    k_bin  <<<98, 1024, 0, stream>>>(src, dst, gcur, staging);
    k_bscan<<<1, 512, 0, stream>>>(gcur, ebase);
    k_build<<<NB, 256, 0, stream>>>(staging, gcur, ebase, offs, ss);

    // 3 GIN layers: agg(xb -> hb), mlp(hb -> xb or out)
    for (int l = 0; l < NUM_LAYERS; ++l) {
        k_agg<<<12500, 256, 0, stream>>>(xb, offs, ss, hb);
        const unsigned short* w1l = wb + (size_t)l * 16384;
        const unsigned short* w2l = wb + (size_t)(3 + l) * 16384;
        const float* b1l = b1 + (size_t)l * DIM;
        const float* b2l = b2 + (size_t)l * DIM;
        if (l < NUM_LAYERS - 1)
            k_mlp<0><<<1563, 256, 0, stream>>>(hb, w1l, b1l, w2l, b2l, xb, nullptr);
        else
            k_mlp<1><<<1563, 256, 0, stream>>>(hb, w1l, b1l, w2l, b2l, nullptr, out);
    }
}

// Round 5
// 317.403 us; speedup vs baseline: 2.9387x; 1.3232x over previous
//
#include <hip/hip_runtime.h>

#define N_NODES   100000
#define N_EDGES   1600000
#define DIM       128
#define NUM_LAYERS 3

#define NB   391          // buckets of 256 dst-nodes
#define BCAP 8192         // staging capacity per bucket (mean 4092, sigma 64)

typedef __attribute__((ext_vector_type(8))) short short8;
typedef __attribute__((ext_vector_type(4))) float f32x4;

#define MFMA_BF16(acc, a, b) \
    asm("v_mfma_f32_16x16x32_bf16 %0, %1, %2, %0" : "+v"(acc) : "v"(a), "v"(b))

__device__ __forceinline__ unsigned short f2bf(float f) {
    unsigned int u = __builtin_bit_cast(unsigned int, f);
    unsigned int r = (u + 0x7FFFu + ((u >> 16) & 1u)) >> 16;   // RNE
    return (unsigned short)r;
}
__device__ __forceinline__ float bflo(unsigned int p) {
    return __builtin_bit_cast(float, p << 16);
}
__device__ __forceinline__ float bfhi(unsigned int p) {
    return __builtin_bit_cast(float, p & 0xFFFF0000u);
}

// ---------------- prep: f32 -> bf16 ----------------

__global__ void k_cvt(const float* __restrict__ x, unsigned short* __restrict__ xb) {
    int i = blockIdx.x * 256 + threadIdx.x;
    float4 v = ((const float4*)x)[i];
    uint2 o;
    o.x = (unsigned int)f2bf(v.x) | ((unsigned int)f2bf(v.y) << 16);
    o.y = (unsigned int)f2bf(v.z) | ((unsigned int)f2bf(v.w) << 16);
    ((uint2*)xb)[i] = o;
}

__global__ void k_wprep(const float* __restrict__ W1, const float* __restrict__ W2,
                        unsigned short* __restrict__ wb) {
    int o = blockIdx.x * 256 + threadIdx.x;
    int m   = o >> 14;
    int idx = o & 16383;
    int i    = idx & 7;
    int lane = (idx >> 3) & 63;
    int kk   = (idx >> 9) & 3;
    int t    = idx >> 11;
    int k = kk * 32 + (lane >> 4) * 8 + i;
    int n = t * 16 + (lane & 15);
    const float* Wsrc = (m < 3) ? (W1 + (size_t)m * 16384) : (W2 + (size_t)(m - 3) * 16384);
    wb[o] = f2bf(Wsrc[k * 128 + n]);
}

// ---------------- CSR build: bucketed counting sort ----------------

__global__ void k_binit(int* __restrict__ gcur) {
    int i = threadIdx.x;
    if (i < NB) gcur[i] = i * BCAP;
}

__global__ __launch_bounds__(1024) void k_bin(
        const int* __restrict__ src, const int* __restrict__ dst,
        int* __restrict__ gcur, unsigned int* __restrict__ staging) {
    __shared__ int h[NB];
    __shared__ int base[NB];
    int tid = threadIdx.x;
    for (int i = tid; i < NB; i += 1024) h[i] = 0;
    __syncthreads();
    int e0 = blockIdx.x * 16384;
    unsigned int rec[16];
    int bk[16];
    #pragma unroll
    for (int k = 0; k < 16; ++k) {
        int e = e0 + k * 1024 + tid;
        if (e < N_EDGES) {
            int d = dst[e];
            int b = d >> 8;
            bk[k] = b;
            rec[k] = (unsigned int)src[e] | ((unsigned int)(d & 255) << 17);
            atomicAdd(&h[b], 1);
        } else bk[k] = -1;
    }
    __syncthreads();
    for (int i = tid; i < NB; i += 1024) {
        int c = h[i];
        base[i] = (c > 0) ? atomicAdd(&gcur[i], c) : 0;
    }
    __syncthreads();
    for (int i = tid; i < NB; i += 1024) h[i] = 0;
    __syncthreads();
    #pragma unroll
    for (int k = 0; k < 16; ++k) {
        if (bk[k] >= 0) {
            int p = base[bk[k]] + atomicAdd(&h[bk[k]], 1);
            staging[p] = rec[k];
        }
    }
}

__global__ void k_bscan(const int* __restrict__ gcur, int* __restrict__ ebase) {
    __shared__ int s[512];
    int t = threadIdx.x;
    int v = (t < NB) ? (gcur[t] - t * BCAP) : 0;
    s[t] = v;
    __syncthreads();
    for (int off = 1; off < 512; off <<= 1) {
        int tmp = 0;
        if (t >= off) tmp = s[t - off];
        __syncthreads();
        if (t >= off) s[t] += tmp;
        __syncthreads();
    }
    if (t < NB) ebase[t] = s[t] - v;
}

__global__ __launch_bounds__(256) void k_build(
        const unsigned int* __restrict__ staging, const int* __restrict__ gcur,
        const int* __restrict__ ebase, int* __restrict__ offs, int* __restrict__ ss) {
    __shared__ int h[256];
    __shared__ int s[256];
    int b = blockIdx.x, t = threadIdx.x;
    int cnt = gcur[b] - b * BCAP;
    const unsigned int* seg = staging + (size_t)b * BCAP;
    h[t] = 0;
    __syncthreads();
    for (int i = t; i < cnt; i += 256) atomicAdd(&h[seg[i] >> 17], 1);
    __syncthreads();
    int v = h[t];
    s[t] = v;
    __syncthreads();
    for (int off = 1; off < 256; off <<= 1) {
        int tmp = 0;
        if (t >= off) tmp = s[t - off];
        __syncthreads();
        if (t >= off) s[t] += tmp;
        __syncthreads();
    }
    int eb = ebase[b];
    int excl = eb + s[t] - v;
    offs[b * 256 + t] = excl;
    __syncthreads();
    h[t] = excl;
    __syncthreads();
    for (int i = t; i < cnt; i += 256) {
        unsigned int r = seg[i];
        int pos = atomicAdd(&h[r >> 17], 1);
        ss[pos] = (int)(r & 0x1FFFFu);
    }
}

// ---------------- Aggregation (bf16): h[i] = x[i] + sum_j x[j] ----------------
// 8 nodes / 256-thread block; 32 lanes per node, one uint2 (4 bf16) per lane.
// Row stride is DIM ushorts: lane's uint2 lives at xb + node*DIM + lane*4.
// Unroll-8 batches 8 independent row gathers to break the idx->row latency chain.

__global__ void k_agg(const unsigned short* __restrict__ xb, const int* __restrict__ offs,
                      const int* __restrict__ ss, unsigned short* __restrict__ hb) {
    int g    = threadIdx.x >> 5;
    int lane = threadIdx.x & 31;
    int node = blockIdx.x * 8 + g;
    uint2 sv = *(const uint2*)(xb + (size_t)node * DIM + lane * 4);
    float a0 = bflo(sv.x), a1 = bfhi(sv.x), a2 = bflo(sv.y), a3 = bfhi(sv.y);
    int start = offs[node];
    int end   = offs[node + 1];
    int e = start;
    int n8 = start + ((end - start) & ~7);
    for (; e < n8; e += 8) {
        int s0 = ss[e + 0], s1 = ss[e + 1], s2 = ss[e + 2], s3 = ss[e + 3];
        int s4 = ss[e + 4], s5 = ss[e + 5], s6 = ss[e + 6], s7 = ss[e + 7];
        uint2 v0 = *(const uint2*)(xb + (size_t)s0 * DIM + lane * 4);
        uint2 v1 = *(const uint2*)(xb + (size_t)s1 * DIM + lane * 4);
        uint2 v2 = *(const uint2*)(xb + (size_t)s2 * DIM + lane * 4);
        uint2 v3 = *(const uint2*)(xb + (size_t)s3 * DIM + lane * 4);
        uint2 v4 = *(const uint2*)(xb + (size_t)s4 * DIM + lane * 4);
        uint2 v5 = *(const uint2*)(xb + (size_t)s5 * DIM + lane * 4);
        uint2 v6 = *(const uint2*)(xb + (size_t)s6 * DIM + lane * 4);
        uint2 v7 = *(const uint2*)(xb + (size_t)s7 * DIM + lane * 4);
        a0 += bflo(v0.x) + bflo(v1.x) + bflo(v2.x) + bflo(v3.x)
            + bflo(v4.x) + bflo(v5.x) + bflo(v6.x) + bflo(v7.x);
        a1 += bfhi(v0.x) + bfhi(v1.x) + bfhi(v2.x) + bfhi(v3.x)
            + bfhi(v4.x) + bfhi(v5.x) + bfhi(v6.x) + bfhi(v7.x);
        a2 += bflo(v0.y) + bflo(v1.y) + bflo(v2.y) + bflo(v3.y)
            + bflo(v4.y) + bflo(v5.y) + bflo(v6.y) + bflo(v7.y);
        a3 += bfhi(v0.y) + bfhi(v1.y) + bfhi(v2.y) + bfhi(v3.y)
            + bfhi(v4.y) + bfhi(v5.y) + bfhi(v6.y) + bfhi(v7.y);
    }
    for (; e < end; ++e) {
        int sidx = ss[e];
        uint2 v = *(const uint2*)(xb + (size_t)sidx * DIM + lane * 4);
        a0 += bflo(v.x); a1 += bfhi(v.x); a2 += bflo(v.y); a3 += bfhi(v.y);
    }
    uint2 o;
    o.x = (unsigned int)f2bf(a0) | ((unsigned int)f2bf(a1) << 16);
    o.y = (unsigned int)f2bf(a2) | ((unsigned int)f2bf(a3) << 16);
    *(uint2*)(hb + (size_t)node * DIM + lane * 4) = o;
}

// ---------------- MFMA MLP ----------------

template <int FINAL>
__global__ __launch_bounds__(256) void k_mlp(
        const unsigned short* __restrict__ hb,
        const unsigned short* __restrict__ w1b, const float* __restrict__ b1,
        const unsigned short* __restrict__ w2b, const float* __restrict__ b2,
        unsigned short* __restrict__ outb, float* __restrict__ outf) {
    __shared__ unsigned short Ts[4][16][136];
    int tid  = threadIdx.x;
    int w    = tid >> 6;
    int lane = tid & 63;
    int r0   = blockIdx.x * 64 + w * 16;
    bool live = (r0 < N_NODES);
    if (!live) r0 = N_NODES - 16;
    int lrow = lane & 15;
    int lgrp = lane >> 4;

    const short8* hb8  = (const short8*)hb;
    const short8* w1f  = (const short8*)w1b;
    const short8* w2f  = (const short8*)w2b;

    f32x4 acc[8];
    #pragma unroll
    for (int t = 0; t < 8; ++t) acc[t] = (f32x4){0.f, 0.f, 0.f, 0.f};

    #pragma unroll
    for (int kk = 0; kk < 4; ++kk) {
        short8 a = hb8[(size_t)(r0 + lrow) * 16 + kk * 4 + lgrp];
        const short8* bp = w1f + kk * 64 + lane;
        #pragma unroll
        for (int t = 0; t < 8; ++t) {
            short8 b = bp[t * 256];
            MFMA_BF16(acc[t], a, b);
        }
    }

    #pragma unroll
    for (int t = 0; t < 8; ++t) {
        float bb = b1[t * 16 + lrow];
        #pragma unroll
        for (int r = 0; r < 4; ++r) {
            float v = acc[t][r] + bb;
            v = fmaxf(v, 0.f);
            Ts[w][lgrp * 4 + r][t * 16 + lrow] = f2bf(v);
        }
        acc[t] = (f32x4){0.f, 0.f, 0.f, 0.f};
    }
    __syncthreads();

    #pragma unroll
    for (int kk = 0; kk < 4; ++kk) {
        short8 a = *(const short8*)&Ts[w][lrow][kk * 32 + lgrp * 8];
        const short8* bp = w2f + kk * 64 + lane;
        #pragma unroll
        for (int t = 0; t < 8; ++t) {
            short8 b = bp[t * 256];
            MFMA_BF16(acc[t], a, b);
        }
    }

    #pragma unroll
    for (int t = 0; t < 8; ++t) {
        float bb = b2[t * 16 + lrow];
        #pragma unroll
        for (int r = 0; r < 4; ++r) {
            float v = acc[t][r] + bb;
            size_t oi = (size_t)(r0 + lgrp * 4 + r) * DIM + t * 16 + lrow;
            if (FINAL) {
                if (live) outf[oi] = v;
            } else {
                v = fmaxf(v, 0.f);
                if (live) outb[oi] = f2bf(v);
            }
        }
    }
}

// ---------------- launch ----------------

extern "C" void kernel_launch(void* const* d_in, const int* in_sizes, int n_in,
                              void* d_out, int out_size, void* d_ws, size_t ws_size,
                              hipStream_t stream) {
    const float* x  = (const float*)d_in[0];
    const int*   ei = (const int*)d_in[1];
    const float* W1 = (const float*)d_in[2];
    const float* b1 = (const float*)d_in[3];
    const float* W2 = (const float*)d_in[4];
    const float* b2 = (const float*)d_in[5];
    float* out = (float*)d_out;

    const int* src = ei;
    const int* dst = ei + N_EDGES;

    char* ws = (char*)d_ws;
    int* gcur  = (int*)ws; ws += 2048;
    int* ebase = (int*)ws; ws += 2048;
    int* offs  = (int*)ws; ws += 100352 * 4;
    int* ss    = (int*)ws; ws += (size_t)N_EDGES * 4;
    unsigned short* wb = (unsigned short*)ws; ws += 6 * 16384 * 2;
    unsigned short* hb = (unsigned short*)ws;
    unsigned int* staging = (unsigned int*)hb;          // aliases hb, dead before first k_agg
    ws += (size_t)N_NODES * DIM * 2;
    unsigned short* xb = (unsigned short*)ws; ws += (size_t)N_NODES * DIM * 2;

    // prep
    k_cvt  <<<12500, 256, 0, stream>>>(x, xb);
    k_wprep<<<384,   256, 0, stream>>>(W1, W2, wb);

    // CSR build: bucketed counting sort
    k_binit<<<1, 512, 0, stream>>>(gcur);
    k_bin  <<<98, 1024, 0, stream>>>(src, dst, gcur, staging);
    k_bscan<<<1, 512, 0, stream>>>(gcur, ebase);
    k_build<<<NB, 256, 0, stream>>>(staging, gcur, ebase, offs, ss);

    // 3 GIN layers: agg(xb -> hb), mlp(hb -> xb or out)
    for (int l = 0; l < NUM_LAYERS; ++l) {
        k_agg<<<12500, 256, 0, stream>>>(xb, offs, ss, hb);
        const unsigned short* w1l = wb + (size_t)l * 16384;
        const unsigned short* w2l = wb + (size_t)(3 + l) * 16384;
        const float* b1l = b1 + (size_t)l * DIM;
        const float* b2l = b2 + (size_t)l * DIM;
        if (l < NUM_LAYERS - 1)
            k_mlp<0><<<1563, 256, 0, stream>>>(hb, w1l, b1l, w2l, b2l, xb, nullptr);
        else
            k_mlp<1><<<1563, 256, 0, stream>>>(hb, w1l, b1l, w2l, b2l, nullptr, out);
    }
}